// Round 6
// baseline (519.097 us; speedup 1.0000x reference)
//
#include <hip/hip_runtime.h>

// Problem constants
#define V 100000
#define VP 100096           // V rounded up to 128 (GEMM row tile) and 4 (gather waves/block)
#define E_EDGES 524288
#define HALF 262144
#define D 128
#define NREL 474
#define BN_EPS 1e-5f
#define NBLK 98             // ceil(V/1024) scan blocks

#define ROWTILES 782        // VP / 128
#define PROWS (ROWTILES * 8)// per-(tile,wave) BN partial rows
#define GEMM_PBLK 512       // persistent gemm blocks (2 per CU)
#define RED_BLKS 98         // 98 * 64 >= PROWS reduce blocks
#define RELB 237            // NREL/2 blocks in final_k
#define BNBLK 12500         // V*D/4/256 blocks in final_k

#define LDK 392   // legacy A-tile LDS row stride in u16
#define LDB 40    // legacy B-tile LDS row stride in u16

typedef unsigned short u16;
typedef unsigned int u32;
typedef unsigned long long u64;
typedef __attribute__((ext_vector_type(8))) short short8;
typedef __attribute__((ext_vector_type(4))) float f32x4;

__device__ __forceinline__ u16 f2bf(float f) {
    union { float f; u32 u; } v; v.f = f;
    u32 u = v.u;
    return (u16)((u + 0x7fffu + ((u >> 16) & 1u)) >> 16);  // RNE
}
__device__ __forceinline__ u32 pk2(float a, float b) {
    return (u32)f2bf(a) | ((u32)f2bf(b) << 16);
}

// ---------------------------------------------------------------------------
// K1: histogram of dst (shared by both paths)
// ---------------------------------------------------------------------------
__global__ __launch_bounds__(256) void hist_k(const int* __restrict__ dst, u32* __restrict__ cnt) {
    int e = blockIdx.x * 256 + threadIdx.x;
    if (e >= E_EDGES) return;
    u32 d = (u32)dst[e];
    if (d >= V) d = 0;
    atomicAdd(&cnt[d], 1u);
}

// ---------------------------------------------------------------------------
// Hierarchical exclusive scan (block-local only; block offsets applied at use)
// ---------------------------------------------------------------------------
__global__ __launch_bounds__(1024) void scanA_k(const u32* __restrict__ cnt,
                                                u32* __restrict__ cursor,
                                                u32* __restrict__ bsum) {
    __shared__ u32 wsum[16];
    int tid = threadIdx.x, wid = tid >> 6, lane = tid & 63;
    int idx = blockIdx.x * 1024 + tid;
    u32 v = (idx < V) ? cnt[idx] : 0u;
    u32 s = v;
#pragma unroll
    for (int o = 1; o < 64; o <<= 1) {
        u32 t = __shfl_up(s, o, 64);
        if (lane >= o) s += t;
    }
    if (lane == 63) wsum[wid] = s;
    __syncthreads();
    if (wid == 0) {
        u32 wv = (lane < 16) ? wsum[lane] : 0u;
#pragma unroll
        for (int o = 1; o < 16; o <<= 1) {
            u32 t = __shfl_up(wv, o, 64);
            if (lane >= o) wv += t;
        }
        if (lane < 16) wsum[lane] = wv;
    }
    __syncthreads();
    u32 wprev = wid ? wsum[wid - 1] : 0u;
    if (idx < V) cursor[idx] = s + wprev - v;           // block-local exclusive
    if (tid == 0) bsum[blockIdx.x] = wsum[15];          // block total
}

// scanB (block 0) merged with the one-time B transpose (blocks 1..128)
__global__ __launch_bounds__(128) void scanBbt_k(
    u32* __restrict__ bsum,
    const float* __restrict__ in_w, const float* __restrict__ out_w,
    const float* __restrict__ loop_w, u16* __restrict__ Bt) {
    if (blockIdx.x > 0) {
        int n = blockIdx.x - 1;   // 0..127 output column
        int t = threadIdx.x;      // 0..127 k within segment
        const float* Ws[3] = {in_w, out_w, loop_w};
#pragma unroll
        for (int seg = 0; seg < 3; seg++)
            Bt[(size_t)n * 384 + seg * 128 + t] = f2bf(Ws[seg][(size_t)t * D + n]);
        return;
    }
    __shared__ u32 wtot;
    int t = threadIdx.x, lane = t & 63, w = t >> 6;
    u32 v = (t < NBLK) ? bsum[t] : 0u;
    u32 s = v;
#pragma unroll
    for (int o = 1; o < 64; o <<= 1) {
        u32 x = __shfl_up(s, o, 64);
        if (lane >= o) s += x;
    }
    if (w == 0 && lane == 63) wtot = s;
    __syncthreads();
    u32 add = (w == 1) ? wtot : 0u;
    if (t < NBLK) bsum[t] = add + s - v;                // exclusive prefix of block totals
}

// ---------------------------------------------------------------------------
// bucket-fill: slot = local prefix + bsum offset. rec = {src,etype,half|norm}
// Post: cursor[v] = LOCAL bucket end (global end = cursor[v] + bsum[v>>10]).
// All fields clamped here, so gather's decode needs no clamps.
// ---------------------------------------------------------------------------
__global__ __launch_bounds__(256) void fill_rec_k(
    const int* __restrict__ dst, const int* __restrict__ src, const int* __restrict__ etype,
    const float* __restrict__ enorm, u32* __restrict__ cursor, const u32* __restrict__ bsum,
    u64* __restrict__ rec) {
    int e = blockIdx.x * 256 + threadIdx.x;
    if (e >= E_EDGES) return;
    u32 d = (u32)dst[e];   if (d >= V) d = 0;
    u32 s = (u32)src[e];   if (s >= V) s = 0;
    u32 t = (u32)etype[e]; if (t >= NREL) t = 0;
    float nm = enorm[e];
    u32 w = s | (t << 17) | ((e < HALF ? 0u : 1u) << 26);
    u32 slot = atomicAdd(&cursor[d], 1u) + bsum[d >> 10];
    u64 r = (u64)w | ((u64)__float_as_uint(nm) << 32);
    if (slot < E_EDGES) rec[slot] = r;
}

// ---------------------------------------------------------------------------
// Gather v6. One wave per node, zero LDS, unconditional 4-wide rounds.
// Out-of-bucket records are fully clamped (s=0, t=0, nm=0): their x/rel
// reads hit the L2-hot row 0 instead of random next-bucket rows, so the
// tail costs no HBM/L3 traffic (R5's nm-only clamp leaked ~70 MB).
// ---------------------------------------------------------------------------
struct Rec { u32 s, t, hf; float nm; };
__device__ __forceinline__ Rec dec(u64 r) {
    Rec q; u32 w = (u32)r;
    q.s = w & 0x1FFFFu;          // < V guaranteed by fill_rec (pad decodes to 0)
    q.t = (w >> 17) & 0x1FFu;    // < NREL guaranteed by fill_rec
    q.hf = (w >> 26) & 1u;
    q.nm = __uint_as_float((u32)(r >> 32));
    return q;
}

__global__ __launch_bounds__(256) void gather_k(
    const float* __restrict__ x, const float* __restrict__ rel,
    const u32* __restrict__ cursor, const u32* __restrict__ cnt,
    const u32* __restrict__ bsum, const u64* __restrict__ rec, u16* __restrict__ Aagg) {
    int wave = threadIdx.x >> 6, lane = threadIdx.x & 63;
    int v = blockIdx.x * 4 + wave;
    u32* arow = (u32*)(Aagg + (size_t)v * 256);
    if (v >= V) { arow[lane] = 0u; arow[64 + lane] = 0u; return; }

    u32 n = cnt[v];
    u32 end = cursor[v] + bsum[v >> 10];
    if (end > E_EDGES) end = E_EDGES;
    if (n > end) n = end;
    u32 p = end - n;
    int col = lane * 2;

    float iA0 = 0.f, iA1 = 0.f, oA0 = 0.f, oA1 = 0.f;
    float iB0 = 0.f, iB1 = 0.f, oB0 = 0.f, oB1 = 0.f;

    for (u32 q = p; q < end; q += 4) {
        // unconditional loads: rec has 8-entry zero pad
        u64 r0 = rec[q], r1 = rec[q + 1], r2 = rec[q + 2], r3 = rec[q + 3];
        Rec q0 = dec(r0), q1 = dec(r1), q2 = dec(r2), q3 = dec(r3);
        // wave-uniform full clamp of out-of-bucket records -> row 0 (L2-hot)
        if (q + 1 >= end) { q1.s = 0; q1.t = 0; q1.nm = 0.f; }
        if (q + 2 >= end) { q2.s = 0; q2.t = 0; q2.nm = 0.f; }
        if (q + 3 >= end) { q3.s = 0; q3.t = 0; q3.nm = 0.f; }
        float2 x0 = *(const float2*)(x + (size_t)q0.s * D + col);
        float2 x1 = *(const float2*)(x + (size_t)q1.s * D + col);
        float2 x2 = *(const float2*)(x + (size_t)q2.s * D + col);
        float2 x3 = *(const float2*)(x + (size_t)q3.s * D + col);
        float2 v0 = *(const float2*)(rel + (size_t)q0.t * D + col);
        float2 v1 = *(const float2*)(rel + (size_t)q1.t * D + col);
        float2 v2 = *(const float2*)(rel + (size_t)q2.t * D + col);
        float2 v3 = *(const float2*)(rel + (size_t)q3.t * D + col);
        float f00 = x0.x * v0.x * q0.nm, f01 = x0.y * v0.y * q0.nm;
        float f10 = x1.x * v1.x * q1.nm, f11 = x1.y * v1.y * q1.nm;
        float f20 = x2.x * v2.x * q2.nm, f21 = x2.y * v2.y * q2.nm;
        float f30 = x3.x * v3.x * q3.nm, f31 = x3.y * v3.y * q3.nm;
        if (q0.hf) { oA0 += f00; oA1 += f01; } else { iA0 += f00; iA1 += f01; }
        if (q1.hf) { oB0 += f10; oB1 += f11; } else { iB0 += f10; iB1 += f11; }
        if (q2.hf) { oA0 += f20; oA1 += f21; } else { iA0 += f20; iA1 += f21; }
        if (q3.hf) { oB0 += f30; oB1 += f31; } else { iB0 += f30; iB1 += f31; }
    }
    arow[lane]      = pk2(iA0 + iB0, iA1 + iB1);   // cols   0..127 (in)
    arow[64 + lane] = pk2(oA0 + oB0, oA1 + oB1);   // cols 128..255 (out)
}

// ---------------------------------------------------------------------------
// GEMM v6: persistent half-B blocks, barrier-free main loop.
// Grid = 512 (2/CU). Block b: half = b>>8, tiles rt = (b&255), +256, ...
// Blocks b and b+256 share row tiles AND XCD (same b%8) -> A/x L2 reuse.
// B (48 KB, swizzled) staged ONCE per block; the tile loop has no barriers:
// BN partials via __shfl_xor reduce, stored to disjoint ps/pq slots.
// ---------------------------------------------------------------------------
__global__ __launch_bounds__(512, 4) void gemm_k(
    const u16* __restrict__ Aagg, const u16* __restrict__ Bt,
    const float* __restrict__ x, const float* __restrict__ loop_rel,
    float* __restrict__ h_out, float* __restrict__ ps, float* __restrict__ pq) {
    __shared__ u16 Bs[64 * 384];          // 49,152 B
    int tid = threadIdx.x, wave = tid >> 6, lane = tid & 63;
    int bid = blockIdx.x;
    int half = bid >> 8;                  // 0..1
    int t0   = bid & 255;                 // starting row tile
    int m16 = lane & 15;
    int kq = (lane >> 4) * 8;

    // ---- stage half-B once (swizzled: byte ^= (row&7)<<4, row stride 768) ----
    {
        const u16* srcB = Bt + (size_t)half * 64 * 384;
        char* bsw = (char*)Bs;
#pragma unroll
        for (int it = 0; it < 6; it++) {
            int c = it * 512 + tid;                      // 0..3071 16B chunks
            int n = c / 48, s = c - n * 48;
            short8 vv = *(const short8*)(srcB + (size_t)n * 384 + s * 8);
            *(short8*)(bsw + (((u32)(n * 768 + s * 16)) ^ (u32)((n & 7) << 4))) = vv;
        }
    }
    __syncthreads();
    const char* bsb = (const char*)Bs;

    for (int rt = t0; rt < ROWTILES; rt += 256) {
        int row0 = rt * 128;
        int gvm = row0 + wave * 16 + m16;
        const u16* arow = Aagg + (size_t)gvm * 256;
        bool vok = gvm < V;

        // prefetch A-frags and loop-path bf16 frags
        short8 af[8];
#pragma unroll
        for (int ks = 0; ks < 8; ks++) af[ks] = *(const short8*)(arow + ks * 32 + kq);
        short8 lf[4];
        {
            const float* xp = x + (size_t)gvm * D + kq;
#pragma unroll
            for (int kk = 0; kk < 4; kk++) {
                float4 x0 = vok ? *(const float4*)(xp + kk * 32)     : (float4){0.f, 0.f, 0.f, 0.f};
                float4 x1 = vok ? *(const float4*)(xp + kk * 32 + 4) : (float4){0.f, 0.f, 0.f, 0.f};
                float4 l0 = *(const float4*)(loop_rel + kk * 32 + kq);
                float4 l1 = *(const float4*)(loop_rel + kk * 32 + kq + 4);
                union { u32 u[4]; short8 s; } c;
                c.u[0] = pk2(x0.x * l0.x, x0.y * l0.y);
                c.u[1] = pk2(x0.z * l0.z, x0.w * l0.w);
                c.u[2] = pk2(x1.x * l1.x, x1.y * l1.y);
                c.u[3] = pk2(x1.z * l1.z, x1.w * l1.w);
                lf[kk] = c.s;
            }
        }

        f32x4 acc[4];
#pragma unroll
        for (int ct = 0; ct < 4; ct++) acc[ct] = (f32x4){0.f, 0.f, 0.f, 0.f};

        // k 0..255 : in/out aggregates
#pragma unroll
        for (int ks = 0; ks < 8; ks++) {
#pragma unroll
            for (int ct = 0; ct < 4; ct++) {
                int n = ct * 16 + m16;
                short8 b = *(const short8*)(bsb + (((u32)(n * 768 + (ks * 32 + kq) * 2)) ^ (u32)((n & 7) << 4)));
                acc[ct] = __builtin_amdgcn_mfma_f32_16x16x32_bf16(af[ks], b, acc[ct], 0, 0, 0);
            }
        }
        // k 256..383 : self-loop path
#pragma unroll
        for (int kk = 0; kk < 4; kk++) {
#pragma unroll
            for (int ct = 0; ct < 4; ct++) {
                int n = ct * 16 + m16;
                short8 b = *(const short8*)(bsb + (((u32)(n * 768 + (256 + kk * 32 + kq) * 2)) ^ (u32)((n & 7) << 4)));
                acc[ct] = __builtin_amdgcn_mfma_f32_16x16x32_bf16(lf[kk], b, acc[ct], 0, 0, 0);
            }
        }

        // epilogue: /3, f32 store, BN partials (shfl reduce, no LDS/barriers)
        int m4 = (lane >> 4) * 4;
        size_t pbase = ((size_t)rt * 8 + wave) * 128 + (size_t)half * 64;
#pragma unroll
        for (int ct = 0; ct < 4; ct++) {
            float ls = 0.f, lq = 0.f;
            f32x4 a = acc[ct];
#pragma unroll
            for (int i = 0; i < 4; i++) {
                int gv = row0 + wave * 16 + m4 + i;
                if (gv < V) {
                    float h = a[i] * (1.0f / 3.0f);
                    h_out[(size_t)gv * D + half * 64 + ct * 16 + m16] = h;
                    ls += h; lq += h * h;
                }
            }
            // reduce across the 4 lane-groups (rows) -> per-column sums
            ls += __shfl_xor(ls, 16); ls += __shfl_xor(ls, 32);
            lq += __shfl_xor(lq, 16); lq += __shfl_xor(lq, 32);
            if ((lane >> 4) == 0) {          // lanes 0..15 store 16 columns
                ps[pbase + ct * 16 + m16] = ls;
                pq[pbase + ct * 16 + m16] = lq;
            }
        }
    }
}

// ---------------------------------------------------------------------------
// Reduce per-(tile,wave) partials -> colsum/colsumsq (few atomics)
// ---------------------------------------------------------------------------
__global__ __launch_bounds__(256) void bn_reduce(
    const float* __restrict__ ps, const float* __restrict__ pq,
    float* __restrict__ colsum, float* __restrict__ colsumsq) {
    int t = threadIdx.x;
    int c = t & 127;
    const float* srcp = (t < 128) ? ps : pq;
    float s = 0.f;
    int r0 = blockIdx.x * 64;
    for (int i = 0; i < 64; i++) {
        int r = r0 + i;
        if (r < PROWS) s += srcp[(size_t)r * 128 + c];
    }
    atomicAdd(((t < 128) ? colsum : colsumsq) + c, s);
}

// ---------------------------------------------------------------------------
// final_k: blocks [0,RELB) do rel @ w_rel; blocks [RELB, RELB+BNBLK) do
// BN+ReLU on h (mean/scale computed inline from colsum -- L2-hot 1 KB).
// ---------------------------------------------------------------------------
__global__ __launch_bounds__(256) void final_k(
    float* __restrict__ hio, const float* __restrict__ colsum, const float* __restrict__ colsumsq,
    const float* __restrict__ rel, const float* __restrict__ w, float* __restrict__ out1) {
    int bid = blockIdx.x;
    if (bid < RELB) {
        __shared__ float rs[2][D];
        int rh = threadIdx.x >> 7, c = threadIdx.x & 127;
        int r = bid * 2 + rh;
        rs[rh][c] = rel[(size_t)r * D + c];
        __syncthreads();
        float s = 0.f;
#pragma unroll 8
        for (int k = 0; k < D; k++) s += rs[rh][k] * w[(size_t)k * D + c];
        out1[(size_t)r * D + c] = s;
        return;
    }
    int idx = ((bid - RELB) * 256 + threadIdx.x) * 4;
    if (idx >= V * D) return;
    int col = idx & (D - 1);
    float4 hv = *(const float4*)(hio + idx);
    float4 ov;
    {
        float m0 = colsum[col + 0] * (1.0f / (float)V);
        float m1 = colsum[col + 1] * (1.0f / (float)V);
        float m2 = colsum[col + 2] * (1.0f / (float)V);
        float m3 = colsum[col + 3] * (1.0f / (float)V);
        if (!isfinite(m0)) m0 = 0.f;
        if (!isfinite(m1)) m1 = 0.f;
        if (!isfinite(m2)) m2 = 0.f;
        if (!isfinite(m3)) m3 = 0.f;
        float v0 = colsumsq[col + 0] * (1.0f / (float)V) - m0 * m0;
        float v1 = colsumsq[col + 1] * (1.0f / (float)V) - m1 * m1;
        float v2 = colsumsq[col + 2] * (1.0f / (float)V) - m2 * m2;
        float v3 = colsumsq[col + 3] * (1.0f / (float)V) - m3 * m3;
        if (!isfinite(v0) || v0 < 0.f) v0 = 0.f;
        if (!isfinite(v1) || v1 < 0.f) v1 = 0.f;
        if (!isfinite(v2) || v2 < 0.f) v2 = 0.f;
        if (!isfinite(v3) || v3 < 0.f) v3 = 0.f;
        float f0 = (hv.x - m0) * rsqrtf(v0 + BN_EPS);
        float f1 = (hv.y - m1) * rsqrtf(v1 + BN_EPS);
        float f2 = (hv.z - m2) * rsqrtf(v2 + BN_EPS);
        float f3 = (hv.w - m3) * rsqrtf(v3 + BN_EPS);
        ov.x = (f0 > 0.f) ? f0 : 0.f;
        ov.y = (f1 > 0.f) ? f1 : 0.f;
        ov.z = (f2 > 0.f) ? f2 : 0.f;
        ov.w = (f3 > 0.f) ? f3 : 0.f;
    }
    *(float4*)(hio + idx) = ov;
}

// ===========================================================================
// LEGACY PATH (verbatim original verified kernels) — used if workspace small
// ===========================================================================
__global__ __launch_bounds__(1024) void scan_k(const u32* __restrict__ cnt,
                                               u32* __restrict__ cursor) {
    __shared__ u32 wsum[16];
    __shared__ u32 carry_s;
    int tid = threadIdx.x, wid = tid >> 6, lane = tid & 63;
    if (tid == 0) carry_s = 0;
    __syncthreads();
    for (int base = 0; base < V; base += 1024) {
        int idx = base + tid;
        u32 v = (idx < V) ? cnt[idx] : 0u;
        u32 s = v;
#pragma unroll
        for (int o = 1; o < 64; o <<= 1) {
            u32 t = __shfl_up(s, o, 64);
            if (lane >= o) s += t;
        }
        if (lane == 63) wsum[wid] = s;
        __syncthreads();
        if (wid == 0) {
            u32 wv = (lane < 16) ? wsum[lane] : 0u;
#pragma unroll
            for (int o = 1; o < 16; o <<= 1) {
                u32 t = __shfl_up(wv, o, 64);
                if (lane >= o) wv += t;
            }
            if (lane < 16) wsum[lane] = wv;
        }
        __syncthreads();
        u32 wprev = (wid == 0) ? 0u : wsum[wid - 1];
        u32 c = carry_s;
        if (idx < V) cursor[idx] = c + s + wprev - v;
        u32 tot = wsum[15];
        __syncthreads();
        if (tid == 0) carry_s = c + tot;
        __syncthreads();
    }
}

__global__ __launch_bounds__(256) void fill_k(
    const int* __restrict__ dst, u32* __restrict__ cursor, u32* __restrict__ eid) {
    int e = blockIdx.x * 256 + threadIdx.x;
    if (e >= E_EDGES) return;
    u32 d = (u32)dst[e];
    if (d >= V) d = 0;
    u32 slot = atomicAdd(&cursor[d], 1u);
    if (slot < E_EDGES) eid[slot] = (u32)e;
}

__global__ __launch_bounds__(256, 1) void fused_k(
    const float* __restrict__ x, const float* __restrict__ rel, const float* __restrict__ loop_rel,
    const float* __restrict__ in_w, const float* __restrict__ out_w, const float* __restrict__ loop_w,
    const float* __restrict__ enorm,
    const int* __restrict__ src, const int* __restrict__ etype,
    const u32* __restrict__ cursor, const u32* __restrict__ cnt,
    const u32* __restrict__ eid,
    float* __restrict__ h_out, float* __restrict__ colsum, float* __restrict__ colsumsq) {
    __shared__ u16 Alds[64 * LDK];
    __shared__ u16 Bs[D * LDB];
    __shared__ float s_sum[D], s_sq[D];

    int tid = threadIdx.x, wave = tid >> 6, lane = tid & 63;
    int row0 = blockIdx.x * 64;

    if (tid < D) { s_sum[tid] = 0.f; s_sq[tid] = 0.f; }

    for (int i = 0; i < 16; i++) {
        int row = wave * 16 + i;
        int gv = row0 + row;
        u32* arow = (u32*)(Alds + row * LDK);
        if (gv < V) {
            float a0 = 0.f, a1 = 0.f, b0 = 0.f, b1 = 0.f;
            float c0 = 0.f, c1 = 0.f, d0 = 0.f, d1 = 0.f;
            u32 n = cnt[gv];
            u32 end = cursor[gv];
            u32 beg = (end >= n) ? end - n : 0u;
            if (beg >= E_EDGES) { beg = 0; n = 0; }
            if (n > E_EDGES - beg) n = E_EDGES - beg;
            u32 nend = beg + n;
            u32 p = beg;
            for (; p + 2 <= nend; p += 2) {
                u32 e0 = eid[p];           if (e0 >= E_EDGES) e0 = 0;
                u32 e1 = eid[p + 1];       if (e1 >= E_EDGES) e1 = 0;
                u32 s0 = (u32)src[e0];     if (s0 >= V) s0 = 0;
                u32 s1 = (u32)src[e1];     if (s1 >= V) s1 = 0;
                u32 t0 = (u32)etype[e0];   if (t0 >= NREL) t0 = 0;
                u32 t1 = (u32)etype[e1];   if (t1 >= NREL) t1 = 0;
                float n0 = enorm[e0];
                float n1 = enorm[e1];
                float2 xv0 = *(const float2*)(x + (size_t)s0 * D + lane * 2);
                float2 xv1 = *(const float2*)(x + (size_t)s1 * D + lane * 2);
                float2 rv0 = *(const float2*)(rel + (size_t)t0 * D + lane * 2);
                float2 rv1 = *(const float2*)(rel + (size_t)t1 * D + lane * 2);
                float f00 = xv0.x * rv0.x * n0, f01 = xv0.y * rv0.y * n0;
                float f10 = xv1.x * rv1.x * n1, f11 = xv1.y * rv1.y * n1;
                if (e0 < HALF) { a0 += f00; a1 += f01; } else { b0 += f00; b1 += f01; }
                if (e1 < HALF) { c0 += f10; c1 += f11; } else { d0 += f10; d1 += f11; }
            }
            if (p < nend) {
                u32 e0 = eid[p];           if (e0 >= E_EDGES) e0 = 0;
                u32 s0 = (u32)src[e0];     if (s0 >= V) s0 = 0;
                u32 t0 = (u32)etype[e0];   if (t0 >= NREL) t0 = 0;
                float n0 = enorm[e0];
                float2 xv0 = *(const float2*)(x + (size_t)s0 * D + lane * 2);
                float2 rv0 = *(const float2*)(rel + (size_t)t0 * D + lane * 2);
                float f00 = xv0.x * rv0.x * n0, f01 = xv0.y * rv0.y * n0;
                if (e0 < HALF) { a0 += f00; a1 += f01; } else { b0 += f00; b1 += f01; }
            }
            a0 += c0; a1 += c1; b0 += d0; b1 += d1;
            float2 xv = *(const float2*)(x + (size_t)gv * D + lane * 2);
            float2 lv = *(const float2*)(loop_rel + lane * 2);
            arow[lane]       = pk2(a0, a1);
            arow[64 + lane]  = pk2(b0, b1);
            arow[128 + lane] = pk2(xv.x * lv.x, xv.y * lv.y);
        } else {
            arow[lane] = 0u; arow[64 + lane] = 0u; arow[128 + lane] = 0u;
        }
    }
    __syncthreads();

    f32x4 acc[8];
#pragma unroll
    for (int ct = 0; ct < 8; ct++) acc[ct] = (f32x4){0.f, 0.f, 0.f, 0.f};

    int m = wave * 16 + (lane & 15);
    int kq = (lane >> 4) * 8;
    int bk = tid >> 3;
    int bn0 = (tid & 7) * 16;

    for (int ks = 0; ks < 12; ks++) {
        int k0 = ks * 32;
        int seg = k0 >> 7;
        int kloc = k0 & 127;
        const float* W = (seg == 0) ? in_w : (seg == 1 ? out_w : loop_w);
#pragma unroll
        for (int j = 0; j < 16; j += 2) {
            float2 w2 = *(const float2*)(W + (size_t)(kloc + bk) * D + bn0 + j);
            Bs[(bn0 + j) * LDB + bk]     = f2bf(w2.x);
            Bs[(bn0 + j + 1) * LDB + bk] = f2bf(w2.y);
        }
        __syncthreads();
        short8 a = *(const short8*)(Alds + m * LDK + k0 + kq);
#pragma unroll
        for (int ct = 0; ct < 8; ct++) {
            short8 b = *(const short8*)(Bs + (ct * 16 + (lane & 15)) * LDB + kq);
            acc[ct] = __builtin_amdgcn_mfma_f32_16x16x32_bf16(a, b, acc[ct], 0, 0, 0);
        }
        __syncthreads();
    }

    int m4 = (lane >> 4) * 4;
#pragma unroll
    for (int ct = 0; ct < 8; ct++) {
        float ls = 0.f, lq = 0.f;
#pragma unroll
        for (int i = 0; i < 4; i++) {
            int gv = row0 + wave * 16 + m4 + i;
            if (gv < V) {
                float h = acc[ct][i] * (1.0f / 3.0f);
                h_out[(size_t)gv * D + ct * 16 + (lane & 15)] = h;
                ls += h; lq += h * h;
            }
        }
        atomicAdd(&s_sum[ct * 16 + (lane & 15)], ls);
        atomicAdd(&s_sq[ct * 16 + (lane & 15)], lq);
    }
    __syncthreads();
    if (tid < D) atomicAdd(&colsum[tid], s_sum[tid]);
    else atomicAdd(&colsumsq[tid - D], s_sq[tid - D]);
}

__global__ void bn_finalize(const float* __restrict__ colsum, const float* __restrict__ colsumsq,
                            float* __restrict__ mean, float* __restrict__ scale) {
    int t = threadIdx.x;
    float m = colsum[t] * (1.0f / (float)V);
    if (!isfinite(m)) m = 0.f;
    float var = colsumsq[t] * (1.0f / (float)V) - m * m;
    if (!isfinite(var) || var < 0.f) var = 0.f;
    mean[t] = m;
    scale[t] = rsqrtf(var + BN_EPS);
}

__global__ __launch_bounds__(256) void bn_relu(
    float* __restrict__ hio, const float* __restrict__ mean, const float* __restrict__ scale) {
    int idx = (blockIdx.x * 256 + threadIdx.x) * 4;
    if (idx >= V * D) return;
    int col = idx & (D - 1);
    float4 hv = *(const float4*)(hio + idx);
    float f0 = (hv.x - mean[col + 0]) * scale[col + 0];
    float f1 = (hv.y - mean[col + 1]) * scale[col + 1];
    float f2 = (hv.z - mean[col + 2]) * scale[col + 2];
    float f3 = (hv.w - mean[col + 3]) * scale[col + 3];
    f0 = (f0 > 0.f) ? f0 : 0.f;
    f1 = (f1 > 0.f) ? f1 : 0.f;
    f2 = (f2 > 0.f) ? f2 : 0.f;
    f3 = (f3 > 0.f) ? f3 : 0.f;
    float4 ov; ov.x = f0; ov.y = f1; ov.z = f2; ov.w = f3;
    *(float4*)(hio + idx) = ov;
}

__global__ __launch_bounds__(128) void rel_gemm(
    const float* __restrict__ rel, const float* __restrict__ w, float* __restrict__ out1) {
    __shared__ float rs[D];
    int t = threadIdx.x;
    int r = blockIdx.x;
    rs[t] = rel[(size_t)r * D + t];
    __syncthreads();
    float s = 0.f;
#pragma unroll 8
    for (int k = 0; k < D; k++) s += rs[k] * w[(size_t)k * D + t];
    out1[(size_t)r * D + t] = s;
}

// ---------------------------------------------------------------------------
extern "C" void kernel_launch(void* const* d_in, const int* in_sizes, int n_in,
                              void* d_out, int out_size, void* d_ws, size_t ws_size,
                              hipStream_t stream) {
    const float* x        = (const float*)d_in[0];
    const float* rel_repr = (const float*)d_in[1];
    const float* enorm    = (const float*)d_in[2];
    const float* in_w     = (const float*)d_in[3];
    const float* out_w    = (const float*)d_in[4];
    const float* loop_w   = (const float*)d_in[5];
    const float* w_rel    = (const float*)d_in[6];
    const float* loop_rel = (const float*)d_in[7];
    // d_in[8] = bias: zeros; per-column constants cancel in BatchNorm anyway.
    const int* src   = (const int*)d_in[9];
    const int* dst   = (const int*)d_in[10];
    const int* etype = (const int*)d_in[11];

    float* out0 = (float*)d_out;                       // h   [V,128]  f32
    float* out1 = (float*)d_out + (size_t)V * D;       // rel [474,128] f32

    char* ws = (char*)d_ws;

    // ---------------- split-path workspace layout (~62 MB) ----------------
    {
        size_t off = 0;
        u32* cnt        = (u32*)(ws + off); off += (size_t)V * 4;        // memset
        float* colsum   = (float*)(ws + off); off += 512;                // memset
        float* colsumsq = (float*)(ws + off); off += 512;                // memset
        size_t zero_bytes = off;                                          // 401,024
        u32* cursor = (u32*)(ws + off); off += (size_t)V * 4;
        u32* bsum   = (u32*)(ws + off); off += 512;
        u16* Bt     = (u16*)(ws + off); off += (size_t)128 * 384 * 2;    // 98,304
        float* ps   = (float*)(ws + off); off += (size_t)PROWS * 128 * 4;
        float* pq   = (float*)(ws + off); off += (size_t)PROWS * 128 * 4;
        u64* rec    = (u64*)(ws + off); off += (size_t)(E_EDGES + 8) * 8; // +8 zero-pad records
        u16* Aagg   = (u16*)(ws + off); off += (size_t)VP * 256 * 2;

        if (ws_size >= off) {
            hipMemsetAsync(d_ws, 0, zero_bytes, stream);
            hipMemsetAsync(rec + E_EDGES, 0, 64, stream);   // zero the rec tail pad
            hist_k<<<(E_EDGES + 255) / 256, 256, 0, stream>>>(dst, cnt);
            scanA_k<<<NBLK, 1024, 0, stream>>>(cnt, cursor, bsum);
            scanBbt_k<<<129, 128, 0, stream>>>(bsum, in_w, out_w, loop_w, Bt);
            fill_rec_k<<<(E_EDGES + 255) / 256, 256, 0, stream>>>(dst, src, etype, enorm, cursor, bsum, rec);
            gather_k<<<VP / 4, 256, 0, stream>>>(x, rel_repr, cursor, cnt, bsum, rec, Aagg);
            gemm_k<<<GEMM_PBLK, 512, 0, stream>>>(Aagg, Bt, x, loop_rel, out0, ps, pq);
            bn_reduce<<<RED_BLKS, 256, 0, stream>>>(ps, pq, colsum, colsumsq);
            final_k<<<RELB + BNBLK, 256, 0, stream>>>(out0, colsum, colsumsq, rel_repr, w_rel, out1);
            return;
        }
    }

    // ---------------- legacy fallback (verbatim original path) ----------------
    {
        size_t off = 0;
        u32* cnt      = (u32*)(ws + off); off += (size_t)V * 4;
        float* colsum = (float*)(ws + off); off += 512;
        float* colsumsq = (float*)(ws + off); off += 512;
        size_t zero_bytes = off;
        u32* cursor   = (u32*)(ws + off); off += (size_t)V * 4;
        float* meanp  = (float*)(ws + off); off += 512;
        float* scalep = (float*)(ws + off); off += 512;
        u32* eid      = (u32*)(ws + off); off += (size_t)E_EDGES * 4;

        if (ws_size < off) return;

        hipMemsetAsync(d_ws, 0, zero_bytes, stream);
        hist_k<<<(E_EDGES + 255) / 256, 256, 0, stream>>>(dst, cnt);
        scan_k<<<1, 1024, 0, stream>>>(cnt, cursor);
        fill_k<<<(E_EDGES + 255) / 256, 256, 0, stream>>>(dst, cursor, eid);
        fused_k<<<(V + 63) / 64, 256, 0, stream>>>(x, rel_repr, loop_rel, in_w, out_w, loop_w,
                                                   enorm, src, etype,
                                                   cursor, cnt, eid,
                                                   out0, colsum, colsumsq);
        bn_finalize<<<1, 128, 0, stream>>>(colsum, colsumsq, meanp, scalep);
        bn_relu<<<(V * D / 4 + 255) / 256, 256, 0, stream>>>(out0, meanp, scalep);
        rel_gemm<<<NREL, 128, 0, stream>>>(rel_repr, w_rel, out1);
    }
}

// Round 7
// 310.934 us; speedup vs baseline: 1.6695x; 1.6695x over previous
//
#include <hip/hip_runtime.h>

// Problem constants
#define V 100000
#define VP 100096           // V rounded up to 128 (GEMM row tile) and 8 (gather nodes/block)
#define E_EDGES 524288
#define HALF 262144
#define D 128
#define NREL 474
#define BN_EPS 1e-5f
#define NBLK 98             // ceil(V/1024) scan blocks

#define ROWTILES 782        // VP / 128
#define GEMM_GRID 1568      // 98 * 16 : pair-swizzled (rt,half) space, guard rt>=ROWTILES
#define RED_BLKS 98         // ceil(782/8) reduce blocks
#define RELB 237            // NREL/2 blocks in final_k
#define BNBLK 12500         // V*D/4/256 blocks in final_k

#define LDK 392   // legacy A-tile LDS row stride in u16
#define LDB 40    // legacy B-tile LDS row stride in u16

typedef unsigned short u16;
typedef unsigned int u32;
typedef unsigned long long u64;
typedef __attribute__((ext_vector_type(8))) short short8;
typedef __attribute__((ext_vector_type(4))) float f32x4;

__device__ __forceinline__ u16 f2bf(float f) {
    union { float f; u32 u; } v; v.f = f;
    u32 u = v.u;
    return (u16)((u + 0x7fffu + ((u >> 16) & 1u)) >> 16);  // RNE
}
__device__ __forceinline__ u32 pk2(float a, float b) {
    return (u32)f2bf(a) | ((u32)f2bf(b) << 16);
}

// ---------------------------------------------------------------------------
// K1: histogram of dst (shared by both paths)
// ---------------------------------------------------------------------------
__global__ __launch_bounds__(256) void hist_k(const int* __restrict__ dst, u32* __restrict__ cnt) {
    int e = blockIdx.x * 256 + threadIdx.x;
    if (e >= E_EDGES) return;
    u32 d = (u32)dst[e];
    if (d >= V) d = 0;
    atomicAdd(&cnt[d], 1u);
}

// ---------------------------------------------------------------------------
// Hierarchical exclusive scan (block-local only; block offsets applied at use)
// ---------------------------------------------------------------------------
__global__ __launch_bounds__(1024) void scanA_k(const u32* __restrict__ cnt,
                                                u32* __restrict__ cursor,
                                                u32* __restrict__ bsum) {
    __shared__ u32 wsum[16];
    int tid = threadIdx.x, wid = tid >> 6, lane = tid & 63;
    int idx = blockIdx.x * 1024 + tid;
    u32 v = (idx < V) ? cnt[idx] : 0u;
    u32 s = v;
#pragma unroll
    for (int o = 1; o < 64; o <<= 1) {
        u32 t = __shfl_up(s, o, 64);
        if (lane >= o) s += t;
    }
    if (lane == 63) wsum[wid] = s;
    __syncthreads();
    if (wid == 0) {
        u32 wv = (lane < 16) ? wsum[lane] : 0u;
#pragma unroll
        for (int o = 1; o < 16; o <<= 1) {
            u32 t = __shfl_up(wv, o, 64);
            if (lane >= o) wv += t;
        }
        if (lane < 16) wsum[lane] = wv;
    }
    __syncthreads();
    u32 wprev = wid ? wsum[wid - 1] : 0u;
    if (idx < V) cursor[idx] = s + wprev - v;           // block-local exclusive
    if (tid == 0) bsum[blockIdx.x] = wsum[15];          // block total
}

// scanB (block 0) merged with the one-time B transpose (blocks 1..128)
__global__ __launch_bounds__(128) void scanBbt_k(
    u32* __restrict__ bsum,
    const float* __restrict__ in_w, const float* __restrict__ out_w,
    const float* __restrict__ loop_w, u16* __restrict__ Bt) {
    if (blockIdx.x > 0) {
        int n = blockIdx.x - 1;   // 0..127 output column
        int t = threadIdx.x;      // 0..127 k within segment
        const float* Ws[3] = {in_w, out_w, loop_w};
#pragma unroll
        for (int seg = 0; seg < 3; seg++)
            Bt[(size_t)n * 384 + seg * 128 + t] = f2bf(Ws[seg][(size_t)t * D + n]);
        return;
    }
    __shared__ u32 wtot;
    int t = threadIdx.x, lane = t & 63, w = t >> 6;
    u32 v = (t < NBLK) ? bsum[t] : 0u;
    u32 s = v;
#pragma unroll
    for (int o = 1; o < 64; o <<= 1) {
        u32 x = __shfl_up(s, o, 64);
        if (lane >= o) s += x;
    }
    if (w == 0 && lane == 63) wtot = s;
    __syncthreads();
    u32 add = (w == 1) ? wtot : 0u;
    if (t < NBLK) bsum[t] = add + s - v;                // exclusive prefix of block totals
}

// ---------------------------------------------------------------------------
// bucket-fill: slot = local prefix + bsum offset. rec = {src,etype,half|norm}
// Post: cursor[v] = LOCAL bucket end (global end = cursor[v] + bsum[v>>10]).
// All fields clamped here, so gather's decode needs no clamps.
// ---------------------------------------------------------------------------
__global__ __launch_bounds__(256) void fill_rec_k(
    const int* __restrict__ dst, const int* __restrict__ src, const int* __restrict__ etype,
    const float* __restrict__ enorm, u32* __restrict__ cursor, const u32* __restrict__ bsum,
    u64* __restrict__ rec) {
    int e = blockIdx.x * 256 + threadIdx.x;
    if (e >= E_EDGES) return;
    u32 d = (u32)dst[e];   if (d >= V) d = 0;
    u32 s = (u32)src[e];   if (s >= V) s = 0;
    u32 t = (u32)etype[e]; if (t >= NREL) t = 0;
    float nm = enorm[e];
    u32 w = s | (t << 17) | ((e < HALF ? 0u : 1u) << 26);
    u32 slot = atomicAdd(&cursor[d], 1u) + bsum[d >> 10];
    u64 r = (u64)w | ((u64)__float_as_uint(nm) << 32);
    if (slot < E_EDGES) rec[slot] = r;
}

// ---------------------------------------------------------------------------
// Gather v7. TWO nodes per wave (32 lanes each), lane owns 4 cols (float4
// loads -> half the load instructions, 2x the in-flight gathers per wave).
// Unconditional 4-record rounds; out-of-bucket indices clamp to the zeroed
// pad record rec[E_EDGES] (s=0,t=0,nm=0 -> L2-hot row 0, contributes 0).
// Round count per wave = max of the two nodes' rounds (excess rounds are
// all-pad and cheap).
// ---------------------------------------------------------------------------
struct Rec { u32 s, t, hf; float nm; };
__device__ __forceinline__ Rec dec(u64 r) {
    Rec q; u32 w = (u32)r;
    q.s = w & 0x1FFFFu;          // < V guaranteed by fill_rec (pad decodes to 0)
    q.t = (w >> 17) & 0x1FFu;    // < NREL guaranteed by fill_rec
    q.hf = (w >> 26) & 1u;
    q.nm = __uint_as_float((u32)(r >> 32));
    return q;
}

__global__ __launch_bounds__(256) void gather_k(
    const float* __restrict__ x, const float* __restrict__ rel,
    const u32* __restrict__ cursor, const u32* __restrict__ cnt,
    const u32* __restrict__ bsum, const u64* __restrict__ rec, u16* __restrict__ Aagg) {
    int tid = threadIdx.x;
    int wave = tid >> 6, lane = tid & 63;
    int l32 = lane & 31;
    int v = blockIdx.x * 8 + wave * 2 + (lane >> 5);   // 8 nodes per block
    int col = l32 * 4;

    u32 n = 0, end = 0;
    if (v < V) {
        n = cnt[v];
        end = cursor[v] + bsum[v >> 10];
        if (end > E_EDGES) end = E_EDGES;
        if (n > end) n = end;
    }
    u32 p = end - n;
    u32 rounds = (n + 3) >> 2;
    u32 ro = (u32)__shfl_xor((int)rounds, 32);
    u32 rw = rounds > ro ? rounds : ro;                // wave-uniform round count

    float iA0=0.f,iA1=0.f,iA2=0.f,iA3=0.f, oA0=0.f,oA1=0.f,oA2=0.f,oA3=0.f;
    float iB0=0.f,iB1=0.f,iB2=0.f,iB3=0.f, oB0=0.f,oB1=0.f,oB2=0.f,oB3=0.f;

    for (u32 r = 0; r < rw; r++) {
        u32 q = p + r * 4;
        u32 i0 = (q     < end) ? q     : (u32)E_EDGES;
        u32 i1 = (q + 1 < end) ? q + 1 : (u32)E_EDGES;
        u32 i2 = (q + 2 < end) ? q + 2 : (u32)E_EDGES;
        u32 i3 = (q + 3 < end) ? q + 3 : (u32)E_EDGES;
        u64 r0 = rec[i0], r1 = rec[i1], r2 = rec[i2], r3 = rec[i3];
        Rec q0 = dec(r0), q1 = dec(r1), q2 = dec(r2), q3 = dec(r3);
        float4 x0 = *(const float4*)(x + (size_t)q0.s * D + col);
        float4 x1 = *(const float4*)(x + (size_t)q1.s * D + col);
        float4 x2 = *(const float4*)(x + (size_t)q2.s * D + col);
        float4 x3 = *(const float4*)(x + (size_t)q3.s * D + col);
        float4 v0 = *(const float4*)(rel + (size_t)q0.t * D + col);
        float4 v1 = *(const float4*)(rel + (size_t)q1.t * D + col);
        float4 v2 = *(const float4*)(rel + (size_t)q2.t * D + col);
        float4 v3 = *(const float4*)(rel + (size_t)q3.t * D + col);
        float f00 = x0.x*v0.x*q0.nm, f01 = x0.y*v0.y*q0.nm, f02 = x0.z*v0.z*q0.nm, f03 = x0.w*v0.w*q0.nm;
        float f10 = x1.x*v1.x*q1.nm, f11 = x1.y*v1.y*q1.nm, f12 = x1.z*v1.z*q1.nm, f13 = x1.w*v1.w*q1.nm;
        float f20 = x2.x*v2.x*q2.nm, f21 = x2.y*v2.y*q2.nm, f22 = x2.z*v2.z*q2.nm, f23 = x2.w*v2.w*q2.nm;
        float f30 = x3.x*v3.x*q3.nm, f31 = x3.y*v3.y*q3.nm, f32_ = x3.z*v3.z*q3.nm, f33 = x3.w*v3.w*q3.nm;
        if (q0.hf) { oA0+=f00; oA1+=f01; oA2+=f02; oA3+=f03; } else { iA0+=f00; iA1+=f01; iA2+=f02; iA3+=f03; }
        if (q1.hf) { oB0+=f10; oB1+=f11; oB2+=f12; oB3+=f13; } else { iB0+=f10; iB1+=f11; iB2+=f12; iB3+=f13; }
        if (q2.hf) { oA0+=f20; oA1+=f21; oA2+=f22; oA3+=f23; } else { iA0+=f20; iA1+=f21; iA2+=f22; iA3+=f23; }
        if (q3.hf) { oB0+=f30; oB1+=f31; oB2+=f32_; oB3+=f33; } else { iB0+=f30; iB1+=f31; iB2+=f32_; iB3+=f33; }
    }
    float a0 = iA0+iB0, a1 = iA1+iB1, a2 = iA2+iB2, a3 = iA3+iB3;
    float b0 = oA0+oB0, b1 = oA1+oB1, b2 = oA2+oB2, b3 = oA3+oB3;
    u32* arow = (u32*)(Aagg + (size_t)v * 256);
    arow[2*l32]        = pk2(a0, a1);    // cols   0..127 (in)
    arow[2*l32+1]      = pk2(a2, a3);
    arow[64 + 2*l32]   = pk2(b0, b1);    // cols 128..255 (out)
    arow[64 + 2*l32+1] = pk2(b2, b3);
}

// ---------------------------------------------------------------------------
// GEMM (R5-proven v5): 128 rows x 64 cols per block, 512 thr, single stage +
// single barrier, A/x register prefetch, swizzled B LDS, XCD-pair swizzle:
// halves (rt,0) and (rt,1) run as bids b and b+8 -> same XCD -> A/x L2 reuse.
// ---------------------------------------------------------------------------
__global__ __launch_bounds__(512) void gemm_k(
    const u16* __restrict__ Aagg, const u16* __restrict__ Bt,
    const float* __restrict__ x, const float* __restrict__ loop_rel,
    float* __restrict__ h_out, float* __restrict__ psum, float* __restrict__ psq) {
    __shared__ u16 Bs[64 * 384];          // 49,152 B
    __shared__ float s_sum[64], s_sq[64];
    int tid = threadIdx.x, wave = tid >> 6, lane = tid & 63;
    int bid = blockIdx.x;
    int rt   = ((bid >> 4) << 3) | (bid & 7);   // row tile
    int half = (bid >> 3) & 1;                  // 64-col half
    if (rt >= ROWTILES) return;                 // uniform whole-block exit
    int row0 = rt * 128;

    if (tid < 64) s_sum[tid] = 0.f;
    else if (tid < 128) s_sq[tid - 64] = 0.f;

    int m16 = lane & 15;
    int kq = (lane >> 4) * 8;
    int gvm = row0 + wave * 16 + m16;
    const u16* arow = Aagg + (size_t)gvm * 256;
    bool vok = gvm < V;

    // ---- prefetch A-frags (8 x 16B) and loop-path bf16 frags ----
    short8 af[8];
#pragma unroll
    for (int ks = 0; ks < 8; ks++) af[ks] = *(const short8*)(arow + ks * 32 + kq);
    short8 lf[4];
    {
        const float* xp = x + (size_t)gvm * D + kq;
#pragma unroll
        for (int kk = 0; kk < 4; kk++) {
            float4 x0 = vok ? *(const float4*)(xp + kk * 32)     : (float4){0.f, 0.f, 0.f, 0.f};
            float4 x1 = vok ? *(const float4*)(xp + kk * 32 + 4) : (float4){0.f, 0.f, 0.f, 0.f};
            float4 l0 = *(const float4*)(loop_rel + kk * 32 + kq);
            float4 l1 = *(const float4*)(loop_rel + kk * 32 + kq + 4);
            union { u32 u[4]; short8 s; } c;
            c.u[0] = pk2(x0.x * l0.x, x0.y * l0.y);
            c.u[1] = pk2(x0.z * l0.z, x0.w * l0.w);
            c.u[2] = pk2(x1.x * l1.x, x1.y * l1.y);
            c.u[3] = pk2(x1.z * l1.z, x1.w * l1.w);
            lf[kk] = c.s;
        }
    }

    // ---- cooperative swizzled copy of B half-tile (64 x 384 u16) ----
    {
        const u16* srcB = Bt + (size_t)half * 64 * 384;
        char* bsw = (char*)Bs;
#pragma unroll
        for (int it = 0; it < 6; it++) {
            int c = it * 512 + tid;                      // 0..3071 16B chunks
            int n = c / 48, s = c - n * 48;
            short8 vv = *(const short8*)(srcB + (size_t)n * 384 + s * 8);
            *(short8*)(bsw + (((u32)(n * 768 + s * 16)) ^ (u32)((n & 7) << 4))) = vv;
        }
    }
    __syncthreads();

    const char* bsb = (const char*)Bs;
    f32x4 acc[4];
#pragma unroll
    for (int ct = 0; ct < 4; ct++) acc[ct] = (f32x4){0.f, 0.f, 0.f, 0.f};

    // k 0..255 : in/out aggregates
#pragma unroll
    for (int ks = 0; ks < 8; ks++) {
#pragma unroll
        for (int ct = 0; ct < 4; ct++) {
            int n = ct * 16 + m16;
            short8 b = *(const short8*)(bsb + (((u32)(n * 768 + (ks * 32 + kq) * 2)) ^ (u32)((n & 7) << 4)));
            acc[ct] = __builtin_amdgcn_mfma_f32_16x16x32_bf16(af[ks], b, acc[ct], 0, 0, 0);
        }
    }
    // k 256..383 : self-loop path
#pragma unroll
    for (int kk = 0; kk < 4; kk++) {
#pragma unroll
        for (int ct = 0; ct < 4; ct++) {
            int n = ct * 16 + m16;
            short8 b = *(const short8*)(bsb + (((u32)(n * 768 + (256 + kk * 32 + kq) * 2)) ^ (u32)((n & 7) << 4)));
            acc[ct] = __builtin_amdgcn_mfma_f32_16x16x32_bf16(lf[kk], b, acc[ct], 0, 0, 0);
        }
    }

    // epilogue: /3, f32 store, BN partials (LDS atomics only)
    int m4 = (lane >> 4) * 4;
#pragma unroll
    for (int ct = 0; ct < 4; ct++) {
        float ls = 0.f, lq = 0.f;
#pragma unroll
        for (int i = 0; i < 4; i++) {
            int gv = row0 + wave * 16 + m4 + i;
            if (gv < V) {
                float h = acc[ct][i] * (1.0f / 3.0f);
                h_out[(size_t)gv * D + half * 64 + ct * 16 + m16] = h;
                ls += h; lq += h * h;
            }
        }
        atomicAdd(&s_sum[ct * 16 + m16], ls);
        atomicAdd(&s_sq[ct * 16 + m16], lq);
    }
    __syncthreads();
    // disjoint 64-col halves of row rt -> no races, plain stores
    if (tid < 64) psum[(size_t)rt * 128 + half * 64 + tid] = s_sum[tid];
    else if (tid < 128) psq[(size_t)rt * 128 + half * 64 + (tid - 64)] = s_sq[tid - 64];
}

// ---------------------------------------------------------------------------
// Reduce per-block partials -> colsum/colsumsq (few atomics)
// ---------------------------------------------------------------------------
__global__ __launch_bounds__(256) void bn_reduce(
    const float* __restrict__ psum, const float* __restrict__ psq,
    float* __restrict__ colsum, float* __restrict__ colsumsq) {
    int t = threadIdx.x;
    int c = t & 127;
    const float* srcp = (t < 128) ? psum : psq;
    float s = 0.f;
    int r0 = blockIdx.x * 8;
#pragma unroll
    for (int i = 0; i < 8; i++) {
        int r = r0 + i;
        if (r < ROWTILES) s += srcp[(size_t)r * 128 + c];
    }
    atomicAdd(((t < 128) ? colsum : colsumsq) + c, s);
}

// ---------------------------------------------------------------------------
// final_k: blocks [0,RELB) do rel @ w_rel; blocks [RELB, RELB+BNBLK) do
// BN+ReLU on h (mean/scale computed inline from colsum -- L2-hot 1 KB).
// ---------------------------------------------------------------------------
__global__ __launch_bounds__(256) void final_k(
    float* __restrict__ hio, const float* __restrict__ colsum, const float* __restrict__ colsumsq,
    const float* __restrict__ rel, const float* __restrict__ w, float* __restrict__ out1) {
    int bid = blockIdx.x;
    if (bid < RELB) {
        __shared__ float rs[2][D];
        int rh = threadIdx.x >> 7, c = threadIdx.x & 127;
        int r = bid * 2 + rh;
        rs[rh][c] = rel[(size_t)r * D + c];
        __syncthreads();
        float s = 0.f;
#pragma unroll 8
        for (int k = 0; k < D; k++) s += rs[rh][k] * w[(size_t)k * D + c];
        out1[(size_t)r * D + c] = s;
        return;
    }
    int idx = ((bid - RELB) * 256 + threadIdx.x) * 4;
    if (idx >= V * D) return;
    int col = idx & (D - 1);
    float4 hv = *(const float4*)(hio + idx);
    float4 ov;
    {
        float m0 = colsum[col + 0] * (1.0f / (float)V);
        float m1 = colsum[col + 1] * (1.0f / (float)V);
        float m2 = colsum[col + 2] * (1.0f / (float)V);
        float m3 = colsum[col + 3] * (1.0f / (float)V);
        if (!isfinite(m0)) m0 = 0.f;
        if (!isfinite(m1)) m1 = 0.f;
        if (!isfinite(m2)) m2 = 0.f;
        if (!isfinite(m3)) m3 = 0.f;
        float v0 = colsumsq[col + 0] * (1.0f / (float)V) - m0 * m0;
        float v1 = colsumsq[col + 1] * (1.0f / (float)V) - m1 * m1;
        float v2 = colsumsq[col + 2] * (1.0f / (float)V) - m2 * m2;
        float v3 = colsumsq[col + 3] * (1.0f / (float)V) - m3 * m3;
        if (!isfinite(v0) || v0 < 0.f) v0 = 0.f;
        if (!isfinite(v1) || v1 < 0.f) v1 = 0.f;
        if (!isfinite(v2) || v2 < 0.f) v2 = 0.f;
        if (!isfinite(v3) || v3 < 0.f) v3 = 0.f;
        float f0 = (hv.x - m0) * rsqrtf(v0 + BN_EPS);
        float f1 = (hv.y - m1) * rsqrtf(v1 + BN_EPS);
        float f2 = (hv.z - m2) * rsqrtf(v2 + BN_EPS);
        float f3 = (hv.w - m3) * rsqrtf(v3 + BN_EPS);
        ov.x = (f0 > 0.f) ? f0 : 0.f;
        ov.y = (f1 > 0.f) ? f1 : 0.f;
        ov.z = (f2 > 0.f) ? f2 : 0.f;
        ov.w = (f3 > 0.f) ? f3 : 0.f;
    }
    *(float4*)(hio + idx) = ov;
}

// ===========================================================================
// LEGACY PATH (verbatim original verified kernels) — used if workspace small
// ===========================================================================
__global__ __launch_bounds__(1024) void scan_k(const u32* __restrict__ cnt,
                                               u32* __restrict__ cursor) {
    __shared__ u32 wsum[16];
    __shared__ u32 carry_s;
    int tid = threadIdx.x, wid = tid >> 6, lane = tid & 63;
    if (tid == 0) carry_s = 0;
    __syncthreads();
    for (int base = 0; base < V; base += 1024) {
        int idx = base + tid;
        u32 v = (idx < V) ? cnt[idx] : 0u;
        u32 s = v;
#pragma unroll
        for (int o = 1; o < 64; o <<= 1) {
            u32 t = __shfl_up(s, o, 64);
            if (lane >= o) s += t;
        }
        if (lane == 63) wsum[wid] = s;
        __syncthreads();
        if (wid == 0) {
            u32 wv = (lane < 16) ? wsum[lane] : 0u;
#pragma unroll
            for (int o = 1; o < 16; o <<= 1) {
                u32 t = __shfl_up(wv, o, 64);
                if (lane >= o) wv += t;
            }
            if (lane < 16) wsum[lane] = wv;
        }
        __syncthreads();
        u32 wprev = (wid == 0) ? 0u : wsum[wid - 1];
        u32 c = carry_s;
        if (idx < V) cursor[idx] = c + s + wprev - v;
        u32 tot = wsum[15];
        __syncthreads();
        if (tid == 0) carry_s = c + tot;
        __syncthreads();
    }
}

__global__ __launch_bounds__(256) void fill_k(
    const int* __restrict__ dst, u32* __restrict__ cursor, u32* __restrict__ eid) {
    int e = blockIdx.x * 256 + threadIdx.x;
    if (e >= E_EDGES) return;
    u32 d = (u32)dst[e];
    if (d >= V) d = 0;
    u32 slot = atomicAdd(&cursor[d], 1u);
    if (slot < E_EDGES) eid[slot] = (u32)e;
}

__global__ __launch_bounds__(256, 1) void fused_k(
    const float* __restrict__ x, const float* __restrict__ rel, const float* __restrict__ loop_rel,
    const float* __restrict__ in_w, const float* __restrict__ out_w, const float* __restrict__ loop_w,
    const float* __restrict__ enorm,
    const int* __restrict__ src, const int* __restrict__ etype,
    const u32* __restrict__ cursor, const u32* __restrict__ cnt,
    const u32* __restrict__ eid,
    float* __restrict__ h_out, float* __restrict__ colsum, float* __restrict__ colsumsq) {
    __shared__ u16 Alds[64 * LDK];
    __shared__ u16 Bs[D * LDB];
    __shared__ float s_sum[D], s_sq[D];

    int tid = threadIdx.x, wave = tid >> 6, lane = tid & 63;
    int row0 = blockIdx.x * 64;

    if (tid < D) { s_sum[tid] = 0.f; s_sq[tid] = 0.f; }

    for (int i = 0; i < 16; i++) {
        int row = wave * 16 + i;
        int gv = row0 + row;
        u32* arow = (u32*)(Alds + row * LDK);
        if (gv < V) {
            float a0 = 0.f, a1 = 0.f, b0 = 0.f, b1 = 0.f;
            float c0 = 0.f, c1 = 0.f, d0 = 0.f, d1 = 0.f;
            u32 n = cnt[gv];
            u32 end = cursor[gv];
            u32 beg = (end >= n) ? end - n : 0u;
            if (beg >= E_EDGES) { beg = 0; n = 0; }
            if (n > E_EDGES - beg) n = E_EDGES - beg;
            u32 nend = beg + n;
            u32 p = beg;
            for (; p + 2 <= nend; p += 2) {
                u32 e0 = eid[p];           if (e0 >= E_EDGES) e0 = 0;
                u32 e1 = eid[p + 1];       if (e1 >= E_EDGES) e1 = 0;
                u32 s0 = (u32)src[e0];     if (s0 >= V) s0 = 0;
                u32 s1 = (u32)src[e1];     if (s1 >= V) s1 = 0;
                u32 t0 = (u32)etype[e0];   if (t0 >= NREL) t0 = 0;
                u32 t1 = (u32)etype[e1];   if (t1 >= NREL) t1 = 0;
                float n0 = enorm[e0];
                float n1 = enorm[e1];
                float2 xv0 = *(const float2*)(x + (size_t)s0 * D + lane * 2);
                float2 xv1 = *(const float2*)(x + (size_t)s1 * D + lane * 2);
                float2 rv0 = *(const float2*)(rel + (size_t)t0 * D + lane * 2);
                float2 rv1 = *(const float2*)(rel + (size_t)t1 * D + lane * 2);
                float f00 = xv0.x * rv0.x * n0, f01 = xv0.y * rv0.y * n0;
                float f10 = xv1.x * rv1.x * n1, f11 = xv1.y * rv1.y * n1;
                if (e0 < HALF) { a0 += f00; a1 += f01; } else { b0 += f00; b1 += f01; }
                if (e1 < HALF) { c0 += f10; c1 += f11; } else { d0 += f10; d1 += f11; }
            }
            if (p < nend) {
                u32 e0 = eid[p];           if (e0 >= E_EDGES) e0 = 0;
                u32 s0 = (u32)src[e0];     if (s0 >= V) s0 = 0;
                u32 t0 = (u32)etype[e0];   if (t0 >= NREL) t0 = 0;
                float n0 = enorm[e0];
                float2 xv0 = *(const float2*)(x + (size_t)s0 * D + lane * 2);
                float2 rv0 = *(const float2*)(rel + (size_t)t0 * D + lane * 2);
                float f00 = xv0.x * rv0.x * n0, f01 = xv0.y * rv0.y * n0;
                if (e0 < HALF) { a0 += f00; a1 += f01; } else { b0 += f00; b1 += f01; }
            }
            a0 += c0; a1 += c1; b0 += d0; b1 += d1;
            float2 xv = *(const float2*)(x + (size_t)gv * D + lane * 2);
            float2 lv = *(const float2*)(loop_rel + lane * 2);
            arow[lane]       = pk2(a0, a1);
            arow[64 + lane]  = pk2(b0, b1);
            arow[128 + lane] = pk2(xv.x * lv.x, xv.y * lv.y);
        } else {
            arow[lane] = 0u; arow[64 + lane] = 0u; arow[128 + lane] = 0u;
        }
    }
    __syncthreads();

    f32x4 acc[8];
#pragma unroll
    for (int ct = 0; ct < 8; ct++) acc[ct] = (f32x4){0.f, 0.f, 0.f, 0.f};

    int m = wave * 16 + (lane & 15);
    int kq = (lane >> 4) * 8;
    int bk = tid >> 3;
    int bn0 = (tid & 7) * 16;

    for (int ks = 0; ks < 12; ks++) {
        int k0 = ks * 32;
        int seg = k0 >> 7;
        int kloc = k0 & 127;
        const float* W = (seg == 0) ? in_w : (seg == 1 ? out_w : loop_w);
#pragma unroll
        for (int j = 0; j < 16; j += 2) {
            float2 w2 = *(const float2*)(W + (size_t)(kloc + bk) * D + bn0 + j);
            Bs[(bn0 + j) * LDB + bk]     = f2bf(w2.x);
            Bs[(bn0 + j + 1) * LDB + bk] = f2bf(w2.y);
        }
        __syncthreads();
        short8 a = *(const short8*)(Alds + m * LDK + k0 + kq);
#pragma unroll
        for (int ct = 0; ct < 8; ct++) {
            short8 b = *(const short8*)(Bs + (ct * 16 + (lane & 15)) * LDB + kq);
            acc[ct] = __builtin_amdgcn_mfma_f32_16x16x32_bf16(a, b, acc[ct], 0, 0, 0);
        }
        __syncthreads();
    }

    int m4 = (lane >> 4) * 4;
#pragma unroll
    for (int ct = 0; ct < 8; ct++) {
        float ls = 0.f, lq = 0.f;
#pragma unroll
        for (int i = 0; i < 4; i++) {
            int gv = row0 + wave * 16 + m4 + i;
            if (gv < V) {
                float h = acc[ct][i] * (1.0f / 3.0f);
                h_out[(size_t)gv * D + ct * 16 + (lane & 15)] = h;
                ls += h; lq += h * h;
            }
        }
        atomicAdd(&s_sum[ct * 16 + (lane & 15)], ls);
        atomicAdd(&s_sq[ct * 16 + (lane & 15)], lq);
    }
    __syncthreads();
    if (tid < D) atomicAdd(&colsum[tid], s_sum[tid]);
    else atomicAdd(&colsumsq[tid - D], s_sq[tid - D]);
}

__global__ void bn_finalize(const float* __restrict__ colsum, const float* __restrict__ colsumsq,
                            float* __restrict__ mean, float* __restrict__ scale) {
    int t = threadIdx.x;
    float m = colsum[t] * (1.0f / (float)V);
    if (!isfinite(m)) m = 0.f;
    float var = colsumsq[t] * (1.0f / (float)V) - m * m;
    if (!isfinite(var) || var < 0.f) var = 0.f;
    mean[t] = m;
    scale[t] = rsqrtf(var + BN_EPS);
}

__global__ __launch_bounds__(256) void bn_relu(
    float* __restrict__ hio, const float* __restrict__ mean, const float* __restrict__ scale) {
    int idx = (blockIdx.x * 256 + threadIdx.x) * 4;
    if (idx >= V * D) return;
    int col = idx & (D - 1);
    float4 hv = *(const float4*)(hio + idx);
    float f0 = (hv.x - mean[col + 0]) * scale[col + 0];
    float f1 = (hv.y - mean[col + 1]) * scale[col + 1];
    float f2 = (hv.z - mean[col + 2]) * scale[col + 2];
    float f3 = (hv.w - mean[col + 3]) * scale[col + 3];
    f0 = (f0 > 0.f) ? f0 : 0.f;
    f1 = (f1 > 0.f) ? f1 : 0.f;
    f2 = (f2 > 0.f) ? f2 : 0.f;
    f3 = (f3 > 0.f) ? f3 : 0.f;
    float4 ov; ov.x = f0; ov.y = f1; ov.z = f2; ov.w = f3;
    *(float4*)(hio + idx) = ov;
}

__global__ __launch_bounds__(128) void rel_gemm(
    const float* __restrict__ rel, const float* __restrict__ w, float* __restrict__ out1) {
    __shared__ float rs[D];
    int t = threadIdx.x;
    int r = blockIdx.x;
    rs[t] = rel[(size_t)r * D + t];
    __syncthreads();
    float s = 0.f;
#pragma unroll 8
    for (int k = 0; k < D; k++) s += rs[k] * w[(size_t)k * D + t];
    out1[(size_t)r * D + t] = s;
}

// ---------------------------------------------------------------------------
extern "C" void kernel_launch(void* const* d_in, const int* in_sizes, int n_in,
                              void* d_out, int out_size, void* d_ws, size_t ws_size,
                              hipStream_t stream) {
    const float* x        = (const float*)d_in[0];
    const float* rel_repr = (const float*)d_in[1];
    const float* enorm    = (const float*)d_in[2];
    const float* in_w     = (const float*)d_in[3];
    const float* out_w    = (const float*)d_in[4];
    const float* loop_w   = (const float*)d_in[5];
    const float* w_rel    = (const float*)d_in[6];
    const float* loop_rel = (const float*)d_in[7];
    // d_in[8] = bias: zeros; per-column constants cancel in BatchNorm anyway.
    const int* src   = (const int*)d_in[9];
    const int* dst   = (const int*)d_in[10];
    const int* etype = (const int*)d_in[11];

    float* out0 = (float*)d_out;                       // h   [V,128]  f32
    float* out1 = (float*)d_out + (size_t)V * D;       // rel [474,128] f32

    char* ws = (char*)d_ws;

    // ---------------- split-path workspace layout (~57 MB) ----------------
    {
        size_t off = 0;
        u32* cnt        = (u32*)(ws + off); off += (size_t)V * 4;        // memset
        float* colsum   = (float*)(ws + off); off += 512;                // memset
        float* colsumsq = (float*)(ws + off); off += 512;                // memset
        size_t zero_bytes = off;                                          // 401,024
        u32* cursor = (u32*)(ws + off); off += (size_t)V * 4;
        u32* bsum   = (u32*)(ws + off); off += 512;
        u16* Bt     = (u16*)(ws + off); off += (size_t)128 * 384 * 2;    // 98,304
        float* psum = (float*)(ws + off); off += (size_t)ROWTILES * 128 * 4;
        float* psq  = (float*)(ws + off); off += (size_t)ROWTILES * 128 * 4;
        u64* rec    = (u64*)(ws + off); off += (size_t)(E_EDGES + 8) * 8; // +8 zero-pad records
        u16* Aagg   = (u16*)(ws + off); off += (size_t)VP * 256 * 2;

        if (ws_size >= off) {
            hipMemsetAsync(d_ws, 0, zero_bytes, stream);
            hipMemsetAsync(rec + E_EDGES, 0, 64, stream);   // zero the rec tail pad
            hist_k<<<(E_EDGES + 255) / 256, 256, 0, stream>>>(dst, cnt);
            scanA_k<<<NBLK, 1024, 0, stream>>>(cnt, cursor, bsum);
            scanBbt_k<<<129, 128, 0, stream>>>(bsum, in_w, out_w, loop_w, Bt);
            fill_rec_k<<<(E_EDGES + 255) / 256, 256, 0, stream>>>(dst, src, etype, enorm, cursor, bsum, rec);
            gather_k<<<VP / 8, 256, 0, stream>>>(x, rel_repr, cursor, cnt, bsum, rec, Aagg);
            gemm_k<<<GEMM_GRID, 512, 0, stream>>>(Aagg, Bt, x, loop_rel, out0, psum, psq);
            bn_reduce<<<RED_BLKS, 256, 0, stream>>>(psum, psq, colsum, colsumsq);
            final_k<<<RELB + BNBLK, 256, 0, stream>>>(out0, colsum, colsumsq, rel_repr, w_rel, out1);
            return;
        }
    }

    // ---------------- legacy fallback (verbatim original path) ----------------
    {
        size_t off = 0;
        u32* cnt      = (u32*)(ws + off); off += (size_t)V * 4;
        float* colsum = (float*)(ws + off); off += 512;
        float* colsumsq = (float*)(ws + off); off += 512;
        size_t zero_bytes = off;
        u32* cursor   = (u32*)(ws + off); off += (size_t)V * 4;
        float* meanp  = (float*)(ws + off); off += 512;
        float* scalep = (float*)(ws + off); off += 512;
        u32* eid      = (u32*)(ws + off); off += (size_t)E_EDGES * 4;

        if (ws_size < off) return;

        hipMemsetAsync(d_ws, 0, zero_bytes, stream);
        hist_k<<<(E_EDGES + 255) / 256, 256, 0, stream>>>(dst, cnt);
        scan_k<<<1, 1024, 0, stream>>>(cnt, cursor);
        fill_k<<<(E_EDGES + 255) / 256, 256, 0, stream>>>(dst, cursor, eid);
        fused_k<<<(V + 63) / 64, 256, 0, stream>>>(x, rel_repr, loop_rel, in_w, out_w, loop_w,
                                                   enorm, src, etype,
                                                   cursor, cnt, eid,
                                                   out0, colsum, colsumsq);
        bn_finalize<<<1, 128, 0, stream>>>(colsum, colsumsq, meanp, scalep);
        bn_relu<<<(V * D / 4 + 255) / 256, 256, 0, stream>>>(out0, meanp, scalep);
        rel_gemm<<<NREL, 128, 0, stream>>>(rel_repr, w_rel, out1);
    }
}